// Round 16
// baseline (381.969 us; speedup 1.0000x reference)
//
#include <hip/hip_runtime.h>
#include <stdint.h>

// VectorQuantizer: z[32768,512] f32, weight[8192,512] f32 ->
//   out[0 .. 32768*512) = z_q = weight[argmin_k ||z-e_k||^2]  (exact fp32 rows)
//   out[32768*512]      = perplexity
//
// Pipeline (MX-fp8, 256x256 tile, 8 waves, wave tile 64x128):
//  1) k_prep_z: e4m3(-2z) row-major; k_prep_w: e4m3(w) + exact f32 norms c_k
//  2) k_phase1: block 256 tok x 256 codes, 8 waves (4 wrM x 2 wcN), wave tile
//     64x128 = 4mi x 8fj frags of mfma_scale_f32_16x16x128_f8f6f4 (uniform
//     scale 2^0) -> LDS reads 24 b128 per 32 MFMA (ratio 0.75 vs 1.0).
//     A AND B staged per K-step via global_load_lds (the empirically-good
//     FETCH pattern), dbuf 2x64KB, counted vmcnt(8) (8 issues/wave/step),
//     2 raw barriers/step, setprio. acc init = ||e||^2 via C operand ->
//     d~ = c - 2 z.e. Per token: TOP-3 packed keys per 128 cells
//     (cell=(split,wcN,col); 64 codes = 8ct x 8fj) -> slot2 + slot3.
//  3) k_select: global min; MARGIN=16 candidates (m1/m2 direct, full rescan
//     only if m3 in margin) re-ranked with exact f64 dots; histogram; writes
//     z_q row directly.   4) k_perp: perplexity
//
// ws layout (bytes): zb@0 16MB | slot3@16777216 16MB | wb@33554432 4MB |
//   cnorm@41943040 32KB | slot2@41975808 32MB | counts@75661312 32KB

#define NTOK 32768
#define NE   8192
#define DIM  512
#define MARGIN 16.0f

typedef __attribute__((ext_vector_type(8))) int   v8i;
typedef __attribute__((ext_vector_type(4))) int   v4i;
typedef __attribute__((ext_vector_type(4))) float f32x4;

#define SBAR   __builtin_amdgcn_s_barrier()
#define SCHED0 __builtin_amdgcn_sched_barrier(0)
#define SCALE1 0x7F7F7F7F  // e8m0 biased-127 = 2^0 in every byte

__device__ __forceinline__ void gl_lds16(const void* g, void* l) {
  __builtin_amdgcn_global_load_lds(
      (const __attribute__((address_space(1))) void*)g,
      (__attribute__((address_space(3))) void*)l, 16, 0, 0);
}

__device__ __forceinline__ int pk8(float a, float b, float c, float d) {
  int r = __builtin_amdgcn_cvt_pk_fp8_f32(a, b, 0, false);
  return __builtin_amdgcn_cvt_pk_fp8_f32(c, d, r, true);
}

__global__ void k_prep_z(const float* __restrict__ z, int2* __restrict__ zb) {
  int i = blockIdx.x * 256 + threadIdx.x;  // one thread per 8 floats, row-major
  const float4* zp = (const float4*)z + (size_t)i * 2;
  float4 a = zp[0], b = zp[1];
  int2 o;  // e4m3(-2z)
  o.x = pk8(-2.f * a.x, -2.f * a.y, -2.f * a.z, -2.f * a.w);
  o.y = pk8(-2.f * b.x, -2.f * b.y, -2.f * b.z, -2.f * b.w);
  zb[i] = o;
}

__global__ void k_prep_w(const float* __restrict__ w, int2* __restrict__ wb,
                         float* __restrict__ cnorm) {
  int row  = blockIdx.x * 4 + (threadIdx.x >> 6);  // one wave per code row
  int lane = threadIdx.x & 63;
  const float4* wp = (const float4*)(w + (size_t)row * DIM) + lane * 2;
  float4 a = wp[0], b = wp[1];
  int2 o;
  o.x = pk8(a.x, a.y, a.z, a.w);
  o.y = pk8(b.x, b.y, b.z, b.w);
  wb[(size_t)row * 64 + lane] = o;
  float s = a.x * a.x + a.y * a.y + a.z * a.z + a.w * a.w
          + b.x * b.x + b.y * b.y + b.z * b.z + b.w * b.w;
#pragma unroll
  for (int m = 1; m < 64; m <<= 1) s += __shfl_xor(s, m);
  if (lane == 0) cnorm[row] = s;
}

// 512 thr = 8 waves (wrM 0..3 token quarter, wcN 0..1 code half).
// Block 256 tok x 256 codes; wave tile 64x128 = 4mi x 8fj.
// K-step 128 fp8: 128B rows (8 x 16B slots), slot-XOR swizzle c^(row&7).
// dbuf 2x64KB; 8 gl_lds/wave/step (4 A + 4 B); vmcnt(8); 32 K-steps (8ct x 4kc).
// grid 512 = 128 tb x 4 splits, XCD-chunked bijective swizzle.
__global__ void __launch_bounds__(512) k_phase1(
    const unsigned char* __restrict__ zb, const unsigned char* __restrict__ wb,
    const float* __restrict__ cnorm, float* __restrict__ slot2,
    float* __restrict__ slot3) {
  __shared__ char S[2][65536];  // [buf][A: 256 rows x 128B | B: 256 rows x 128B]

  const int tid  = threadIdx.x;
  const int lane = tid & 63;
  const int wv   = tid >> 6;
  const int wrM  = wv >> 1;   // 0..3
  const int wcN  = wv & 1;    // 0..1
  const int swzb  = (blockIdx.x & 7) * 64 + (blockIdx.x >> 3);
  const int split = swzb >> 7;   // 0..3
  const int tb    = swzb & 127;  // 0..127
  const int l15  = lane & 15;

  // staging: lane l -> dest row l>>3, slot l&7; swizzled store slot = c^(row&7)
  // => pre-swizzled source slot = (l&7) ^ ((l>>3)&7).
  const int srcsw = (((lane & 7) ^ ((lane >> 3) & 7)) << 4);
  const unsigned char* zsA = zb + (size_t)(tb * 256 + wv * 32 + (lane >> 3)) * 512 + srcsw;
  const unsigned char* zsB = wb + (size_t)(split * 2048 + wv * 32 + (lane >> 3)) * 512 + srcsw;

  // frag reads: lane wants slots {2g, 2g+1} (g = lane>>4) of row base+l15;
  // stored slot = want ^ (row&7), row&7 == lane&7 (bases are 0 mod 16).
  const int offs0 = ((((lane >> 4) * 2) ^ (lane & 7)) << 4);
  const int offs1 = ((((lane >> 4) * 2 + 1) ^ (lane & 7)) << 4);
  int arow[4], brow[8];
#pragma unroll
  for (int i = 0; i < 4; ++i) arow[i] = (wrM * 64 + i * 16 + l15) * 128;
#pragma unroll
  for (int j = 0; j < 8; ++j) brow[j] = 32768 + (wcN * 128 + j * 16 + l15) * 128;

  const float BIG = 3.0e38f;
  float m1s[4][4], m2s[4][4], m3s[4][4];
#pragma unroll
  for (int mi = 0; mi < 4; ++mi)
#pragma unroll
    for (int r = 0; r < 4; ++r) { m1s[mi][r] = BIG; m2s[mi][r] = BIG; m3s[mi][r] = BIG; }

  const unsigned int KMASK = 0xFFFFE000u;

  // stage K-step g (= ct*4+kc) into buf g&1: A 4 + B 4 gl_lds per wave
  auto stage = [&](int g) {
    char* base = S[g & 1];
    const unsigned char* ga = zsA + ((g & 3) << 7);
#pragma unroll
    for (int r = 0; r < 4; ++r) gl_lds16(ga + r * 4096, base + wv * 4096 + r * 1024);
    const unsigned char* gb = zsB + ((size_t)(g >> 2) << 17) + ((g & 3) << 7);
#pragma unroll
    for (int r = 0; r < 4; ++r) gl_lds16(gb + r * 4096, base + 32768 + wv * 4096 + r * 1024);
  };

  stage(0);
  __syncthreads();  // drains prologue; queue clean

  for (int ct = 0; ct < 8; ++ct) {
    const int codebase = split * 2048 + ct * 256 + wcN * 128 + l15;
    // cf loads are older than stage(g+1) -> drained by kc=0's vmcnt(8)
    float cf[8];
#pragma unroll
    for (int j = 0; j < 8; ++j) cf[j] = cnorm[codebase + j * 16];
    f32x4 acc[4][8];

#pragma unroll 1
    for (int kc = 0; kc < 4; ++kc) {
      const int g = ct * 4 + kc;
      if (g < 31) { stage(g + 1); asm volatile("s_waitcnt vmcnt(8)" ::: "memory"); }
      else        { asm volatile("s_waitcnt vmcnt(0)" ::: "memory"); }
      SBAR; SCHED0;
      const char* P = S[g & 1];
      v8i a[4];
#pragma unroll
      for (int i = 0; i < 4; ++i) {
        v4i lo = *(const v4i*)(P + arow[i] + offs0);
        v4i hi = *(const v4i*)(P + arow[i] + offs1);
        a[i] = __builtin_shufflevector(lo, hi, 0, 1, 2, 3, 4, 5, 6, 7);
      }
      // ---- fj half 0
      {
        v8i b[4];
#pragma unroll
        for (int j = 0; j < 4; ++j) {
          v4i lo = *(const v4i*)(P + brow[j] + offs0);
          v4i hi = *(const v4i*)(P + brow[j] + offs1);
          b[j] = __builtin_shufflevector(lo, hi, 0, 1, 2, 3, 4, 5, 6, 7);
        }
        __builtin_amdgcn_s_setprio(1);
        if (kc == 0) {
#pragma unroll
          for (int mi = 0; mi < 4; ++mi)
#pragma unroll
            for (int j = 0; j < 4; ++j) {
              f32x4 c = {cf[j], cf[j], cf[j], cf[j]};
              acc[mi][j] = __builtin_amdgcn_mfma_scale_f32_16x16x128_f8f6f4(a[mi], b[j], c, 0, 0, 0, SCALE1, 0, SCALE1);
            }
        } else {
#pragma unroll
          for (int mi = 0; mi < 4; ++mi)
#pragma unroll
            for (int j = 0; j < 4; ++j)
              acc[mi][j] = __builtin_amdgcn_mfma_scale_f32_16x16x128_f8f6f4(a[mi], b[j], acc[mi][j], 0, 0, 0, SCALE1, 0, SCALE1);
        }
        __builtin_amdgcn_s_setprio(0);
      }
      // ---- fj half 1
      {
        v8i b[4];
#pragma unroll
        for (int j = 0; j < 4; ++j) {
          v4i lo = *(const v4i*)(P + brow[j + 4] + offs0);
          v4i hi = *(const v4i*)(P + brow[j + 4] + offs1);
          b[j] = __builtin_shufflevector(lo, hi, 0, 1, 2, 3, 4, 5, 6, 7);
        }
        __builtin_amdgcn_s_setprio(1);
        if (kc == 0) {
#pragma unroll
          for (int mi = 0; mi < 4; ++mi)
#pragma unroll
            for (int j = 0; j < 4; ++j) {
              f32x4 c = {cf[j + 4], cf[j + 4], cf[j + 4], cf[j + 4]};
              acc[mi][j + 4] = __builtin_amdgcn_mfma_scale_f32_16x16x128_f8f6f4(a[mi], b[j], c, 0, 0, 0, SCALE1, 0, SCALE1);
            }
        } else {
#pragma unroll
          for (int mi = 0; mi < 4; ++mi)
#pragma unroll
            for (int j = 0; j < 4; ++j)
              acc[mi][j + 4] = __builtin_amdgcn_mfma_scale_f32_16x16x128_f8f6f4(a[mi], b[j], acc[mi][j + 4], 0, 0, 0, SCALE1, 0, SCALE1);
        }
        __builtin_amdgcn_s_setprio(0);
      }
      SBAR;  // reads of buf g&1 done -> step g+2 may overwrite
    }

    // epilogue: acc IS d~ = c - 2 z.e ; pack (quantized d | code), top-3 insert
#pragma unroll
    for (int mi = 0; mi < 4; ++mi) {
#pragma unroll
      for (int r = 0; r < 4; ++r) {
        float M1 = m1s[mi][r], M2 = m2s[mi][r], M3 = m3s[mi][r];
#pragma unroll
        for (int j = 0; j < 8; ++j) {
          float kf = __uint_as_float((__float_as_uint(acc[mi][j][r]) & KMASK) |
                                     (unsigned)(codebase + j * 16));
          float t3 = fminf(M3, fmaxf(M2, kf));
          float t2 = fminf(M2, fmaxf(M1, kf));
          M1 = fminf(M1, kf); M2 = t2; M3 = t3;
        }
        m1s[mi][r] = M1; m2s[mi][r] = M2; m3s[mi][r] = M3;
      }
    }
  }

  // cell = split*32 + wcN*16 + col  (64 codes: 8 ct x 8 fj)
  const int cell = split * 32 + wcN * 16 + l15;
#pragma unroll
  for (int mi = 0; mi < 4; ++mi) {
#pragma unroll
    for (int r = 0; r < 4; ++r) {
      int token = tb * 256 + wrM * 64 + mi * 16 + (lane >> 4) * 4 + r;
      ((float2*)(slot2 + (size_t)token * 256))[cell] = make_float2(m1s[mi][r], m2s[mi][r]);
      slot3[(size_t)token * 128 + cell] = m3s[mi][r];
    }
  }
}

// one wave per token; exact f64 re-rank of margin candidates; writes z_q row.
__global__ void k_select(const float* __restrict__ slot2, const float* __restrict__ slot3,
                         const float* __restrict__ z, const float* __restrict__ w,
                         unsigned int* __restrict__ counts, float* __restrict__ out) {
  const int lane = threadIdx.x & 63;
  const int t = blockIdx.x * 4 + (threadIdx.x >> 6);

  float4 e = *(const float4*)(slot2 + (size_t)t * 256 + lane * 4);  // cells 2l,2l+1 (m1,m2)
  float2 q = *(const float2*)(slot3 + (size_t)t * 128 + lane * 2);  // cells 2l,2l+1 (m3)
  float pk = fminf(e.x, e.z);
#pragma unroll
  for (int m = 1; m < 64; m <<= 1) pk = fminf(pk, __shfl_xor(pk, m));
  const unsigned int mb = __float_as_uint(pk);
  int best = (int)(mb & 0x1FFFu);
  const float thr = __uint_as_float(mb & 0xFFFFE000u) + MARGIN;

  const unsigned int KM = 0xFFFFE000u;
  bool c0 = __uint_as_float(__float_as_uint(e.x) & KM) < thr;
  bool c1 = __uint_as_float(__float_as_uint(e.y) & KM) < thr;
  bool c2 = __uint_as_float(__float_as_uint(e.z) & KM) < thr;
  bool c3 = __uint_as_float(__float_as_uint(e.w) & KM) < thr;
  bool h0 = __uint_as_float(__float_as_uint(q.x) & KM) < thr;  // cell 2l needs full scan
  bool h1 = __uint_as_float(__float_as_uint(q.y) & KM) < thr;  // cell 2l+1
  unsigned long long B0 = __ballot(c0), B1 = __ballot(c1);
  unsigned long long B2 = __ballot(c2), B3 = __ballot(c3);
  unsigned long long H0 = __ballot(h0), H1 = __ballot(h1);
  int nc = __popcll(B0) + __popcll(B1) + __popcll(B2) + __popcll(B3);

  if (nc > 1) {
    const float4* zp = (const float4*)(z + (size_t)t * DIM) + lane * 2;
    float4 za = zp[0], zc = zp[1];
    double bestd = 1e300;
    int besti = NE;

    auto eval = [&](int code) {
      const float4* wp = (const float4*)(w + (size_t)code * DIM) + lane * 2;
      float4 wa = wp[0], wv2 = wp[1];
      double d = (double)wa.x * ((double)wa.x - 2.0 * (double)za.x)
               + (double)wa.y * ((double)wa.y - 2.0 * (double)za.y)
               + (double)wa.z * ((double)wa.z - 2.0 * (double)za.z)
               + (double)wa.w * ((double)wa.w - 2.0 * (double)za.w)
               + (double)wv2.x * ((double)wv2.x - 2.0 * (double)zc.x)
               + (double)wv2.y * ((double)wv2.y - 2.0 * (double)zc.y)
               + (double)wv2.z * ((double)wv2.z - 2.0 * (double)zc.z)
               + (double)wv2.w * ((double)wv2.w - 2.0 * (double)zc.w);
#pragma unroll
      for (int m = 1; m < 64; m <<= 1) d += __shfl_xor(d, m);
      if (d < bestd || (d == bestd && code < besti)) { bestd = d; besti = code; }
    };
    // cell = (split, wcN, col): codes sp*2048 + ct*256 + wcc*128 + fj*16 + col
    auto scan_cell = [&](int cid) {
      int sp = cid >> 5, wcc = (cid >> 4) & 1, col = cid & 15;
      int base = sp * 2048 + wcc * 128 + col;
      for (int ctt = 0; ctt < 8; ++ctt)
        for (int fj = 0; fj < 8; ++fj)
          eval(base + ctt * 256 + fj * 16);
    };

    int i0 = (int)(__float_as_uint(e.x) & 0x1FFFu);
    int i1 = (int)(__float_as_uint(e.y) & 0x1FFFu);
    int i2 = (int)(__float_as_uint(e.z) & 0x1FFFu);
    int i3 = (int)(__float_as_uint(e.w) & 0x1FFFu);
    unsigned long long bm;
    bm = __ballot(c0 && !h0); while (bm) { int s = __ffsll(bm) - 1; bm &= bm - 1; eval(__shfl(i0, s)); }
    bm = __ballot(c1 && !h0); while (bm) { int s = __ffsll(bm) - 1; bm &= bm - 1; eval(__shfl(i1, s)); }
    bm = __ballot(c2 && !h1); while (bm) { int s = __ffsll(bm) - 1; bm &= bm - 1; eval(__shfl(i2, s)); }
    bm = __ballot(c3 && !h1); while (bm) { int s = __ffsll(bm) - 1; bm &= bm - 1; eval(__shfl(i3, s)); }
    bm = H0; while (bm) { int s = __ffsll(bm) - 1; bm &= bm - 1; scan_cell(2 * s); }
    bm = H1; while (bm) { int s = __ffsll(bm) - 1; bm &= bm - 1; scan_cell(2 * s + 1); }
    best = besti;
  }
  if (lane == 0) atomicAdd(&counts[best], 1u);
  // write z_q row (gather merged here)
  const float4* wr4 = (const float4*)(w + (size_t)best * DIM);
  float4* o4 = (float4*)(out + (size_t)t * DIM);
  o4[lane]      = wr4[lane];
  o4[lane + 64] = wr4[lane + 64];
}

__global__ void k_perp(const unsigned int* __restrict__ counts, float* __restrict__ out) {
  __shared__ float red[16];
  float s = 0.f;
  for (int k = threadIdx.x; k < NE; k += 1024) {
    float p = (float)counts[k] * (1.0f / (float)NTOK);
    s += p * logf(p + 1e-10f);
  }
#pragma unroll
  for (int m = 1; m < 64; m <<= 1) s += __shfl_xor(s, m);
  int lane = threadIdx.x & 63, wv = threadIdx.x >> 6;
  if (lane == 0) red[wv] = s;
  __syncthreads();
  if (threadIdx.x == 0) {
    float tot = 0.f;
    for (int i = 0; i < 16; ++i) tot += red[i];
    out[(size_t)NTOK * DIM] = expf(-tot);
  }
}

extern "C" void kernel_launch(void* const* d_in, const int* in_sizes, int n_in,
                              void* d_out, int out_size, void* d_ws, size_t ws_size,
                              hipStream_t stream) {
  const float* z = (const float*)d_in[0];
  const float* w = (const float*)d_in[1];
  float* out = (float*)d_out;
  char* ws = (char*)d_ws;

  unsigned char* zb     = (unsigned char*)(ws);
  float*        slot3   = (float*)(ws + 16777216);
  unsigned char* wb     = (unsigned char*)(ws + 33554432);
  float*        cnorm   = (float*)(ws + 41943040);
  float*        slot2   = (float*)(ws + 41975808);
  unsigned int* counts  = (unsigned int*)(ws + 75661312);

  k_prep_z<<<8192, 256, 0, stream>>>(z, (int2*)zb);
  k_prep_w<<<2048, 256, 0, stream>>>(w, (int2*)wb, cnorm);
  k_phase1<<<512, 512, 0, stream>>>(zb, wb, cnorm, slot2, slot3);
  hipMemsetAsync(counts, 0, NE * sizeof(unsigned int), stream);
  k_select<<<8192, 256, 0, stream>>>(slot2, slot3, z, w, counts, out);
  k_perp<<<1, 1024, 0, stream>>>(counts, out);
}

// Round 17
// 349.878 us; speedup vs baseline: 1.0917x; 1.0917x over previous
//
#include <hip/hip_runtime.h>
#include <stdint.h>

// VectorQuantizer: z[32768,512] f32, weight[8192,512] f32 ->
//   out[0 .. 32768*512) = z_q = weight[argmin_k ||z-e_k||^2]  (exact fp32 rows)
//   out[32768*512]      = perplexity
//
// Pipeline (r15 structure + fully-unrolled kc loop):
//  1) k_prep_z: e4m3(-2z) row-major; k_prep_w: e4m3(w) + exact f32 norms c_k
//  2) k_phase1: 128x128 tile, 4 waves, mfma_scale_f32_16x16x128_f8f6f4
//     (uniform scale 2^0). A AND B staged per K-step via global_load_lds
//     (the empirically-L2-stable FETCH pattern at 2 blocks/CU), dbuf 2x32KB,
//     counted vmcnt(8), 2 raw barriers/step, setprio. kc loop FULLY UNROLLED
//     so stage offsets constant-fold (cuts ~16 VALU/step) and the scheduler
//     gets a 4-step window. acc init = ||e||^2 via C operand -> d~ = c-2z.e.
//     Per token: TOP-3 packed keys per 128 cells -> slot2 + slot3.
//  3) k_select: global min; MARGIN=16 candidates (m1/m2 direct, full 64-code
//     rescan only if m3 in margin) re-ranked with exact f64 dots; histogram;
//     writes z_q row directly.   4) k_perp: perplexity
//
// ws layout (bytes): zb@0 16MB | slot3@16777216 16MB | wb@33554432 4MB |
//   cnorm@41943040 32KB | slot2@41975808 32MB | counts@75661312 32KB

#define NTOK 32768
#define NE   8192
#define DIM  512
#define MARGIN 16.0f

typedef __attribute__((ext_vector_type(8))) int   v8i;
typedef __attribute__((ext_vector_type(4))) int   v4i;
typedef __attribute__((ext_vector_type(4))) float f32x4;

#define SBAR   __builtin_amdgcn_s_barrier()
#define SCHED0 __builtin_amdgcn_sched_barrier(0)
#define SCALE1 0x7F7F7F7F  // e8m0 biased-127 = 2^0 in every byte

__device__ __forceinline__ void gl_lds16(const void* g, void* l) {
  __builtin_amdgcn_global_load_lds(
      (const __attribute__((address_space(1))) void*)g,
      (__attribute__((address_space(3))) void*)l, 16, 0, 0);
}

__device__ __forceinline__ int pk8(float a, float b, float c, float d) {
  int r = __builtin_amdgcn_cvt_pk_fp8_f32(a, b, 0, false);
  return __builtin_amdgcn_cvt_pk_fp8_f32(c, d, r, true);
}

__global__ void k_prep_z(const float* __restrict__ z, int2* __restrict__ zb) {
  int i = blockIdx.x * 256 + threadIdx.x;  // one thread per 8 floats, row-major
  const float4* zp = (const float4*)z + (size_t)i * 2;
  float4 a = zp[0], b = zp[1];
  int2 o;  // e4m3(-2z)
  o.x = pk8(-2.f * a.x, -2.f * a.y, -2.f * a.z, -2.f * a.w);
  o.y = pk8(-2.f * b.x, -2.f * b.y, -2.f * b.z, -2.f * b.w);
  zb[i] = o;
}

__global__ void k_prep_w(const float* __restrict__ w, int2* __restrict__ wb,
                         float* __restrict__ cnorm) {
  int row  = blockIdx.x * 4 + (threadIdx.x >> 6);  // one wave per code row
  int lane = threadIdx.x & 63;
  const float4* wp = (const float4*)(w + (size_t)row * DIM) + lane * 2;
  float4 a = wp[0], b = wp[1];
  int2 o;
  o.x = pk8(a.x, a.y, a.z, a.w);
  o.y = pk8(b.x, b.y, b.z, b.w);
  wb[(size_t)row * 64 + lane] = o;
  float s = a.x * a.x + a.y * a.y + a.z * a.z + a.w * a.w
          + b.x * b.x + b.y * b.y + b.z * b.z + b.w * b.w;
#pragma unroll
  for (int m = 1; m < 64; m <<= 1) s += __shfl_xor(s, m);
  if (lane == 0) cnorm[row] = s;
}

// 256 thr = 4 waves (wr,wc 2x2), tile 128 tok x 128 codes, wave 64x64.
// K-step 128 fp8: rows 128B (8 x 16B slots), slot-XOR swizzle c^(row&7).
// dbuf 2x32KB; 8 gl_lds/wave/step (4 A + 4 B); vmcnt(8); 64 K-steps.
// grid 1024 = 256 tb x 4 splits, XCD-chunked bijective swizzle.
__global__ void __launch_bounds__(256) k_phase1(
    const unsigned char* __restrict__ zb, const unsigned char* __restrict__ wb,
    const float* __restrict__ cnorm, float* __restrict__ slot2,
    float* __restrict__ slot3) {
  __shared__ char S[2][32768];  // [buf][A: 128 rows x 128B | B: 128 rows x 128B]

  const int tid  = threadIdx.x;
  const int lane = tid & 63;
  const int wv   = tid >> 6;
  const int wr   = wv >> 1;
  const int wc   = wv & 1;
  const int swzb  = (blockIdx.x & 7) * 128 + (blockIdx.x >> 3);
  const int split = swzb >> 8;   // 0..3
  const int tb    = swzb & 255;  // 0..255
  const int l15  = lane & 15;

  // staging: lane l -> dest row l>>3, slot l&7; swizzled store slot = c^(row&7)
  // => pre-swizzled source slot = (l&7) ^ ((l>>3)&7).
  const int srcsw = (((lane & 7) ^ ((lane >> 3) & 7)) << 4);
  const unsigned char* zsA = zb + (size_t)(tb * 128 + wv * 32 + (lane >> 3)) * 512 + srcsw;
  const unsigned char* zsB = wb + (size_t)(split * 2048 + wv * 32 + (lane >> 3)) * 512 + srcsw;

  // frag reads: lane wants slots {2g, 2g+1} (g = lane>>4) of row base+l15;
  // stored slot = want ^ (row&7), row&7 == lane&7 (bases are 0 mod 16).
  const int offs0 = ((((lane >> 4) * 2) ^ (lane & 7)) << 4);
  const int offs1 = ((((lane >> 4) * 2 + 1) ^ (lane & 7)) << 4);
  int arow[4], brow[4];
#pragma unroll
  for (int i = 0; i < 4; ++i) {
    arow[i] = (wr * 64 + i * 16 + l15) * 128;
    brow[i] = 16384 + (wc * 64 + i * 16 + l15) * 128;
  }

  const float BIG = 3.0e38f;
  float m1s[4][4], m2s[4][4], m3s[4][4];
#pragma unroll
  for (int mi = 0; mi < 4; ++mi)
#pragma unroll
    for (int r = 0; r < 4; ++r) { m1s[mi][r] = BIG; m2s[mi][r] = BIG; m3s[mi][r] = BIG; }

  const unsigned int KMASK = 0xFFFFE000u;

  // stage K-step g (= ct*4+kc) into buf g&1: A 4 + B 4 gl_lds per wave
  auto stage = [&](int g) {
    char* DA = &S[g & 1][wv * 4096];
    const unsigned char* ga = zsA + ((g & 3) << 7);
#pragma unroll
    for (int r = 0; r < 4; ++r) gl_lds16(ga + r * 4096, DA + r * 1024);
    char* DB = &S[g & 1][16384 + wv * 4096];
    const unsigned char* gb = zsB + ((size_t)(g >> 2) << 16) + ((g & 3) << 7);
#pragma unroll
    for (int r = 0; r < 4; ++r) gl_lds16(gb + r * 4096, DB + r * 1024);
  };

  stage(0);
  __syncthreads();  // drains prologue; queue clean

  for (int ct = 0; ct < 16; ++ct) {
    const int codebase = split * 2048 + ct * 128 + wc * 64 + l15;
    // cf loads are older than stage(g+1) -> drained by kc=0's vmcnt(8)
    float cf0 = cnorm[codebase + 0];
    float cf1 = cnorm[codebase + 16];
    float cf2 = cnorm[codebase + 32];
    float cf3 = cnorm[codebase + 48];
    f32x4 acc[4][4];

#pragma unroll
    for (int kc = 0; kc < 4; ++kc) {
      const int g = ct * 4 + kc;
      if (g < 63) { stage(g + 1); asm volatile("s_waitcnt vmcnt(8)" ::: "memory"); }
      else        { asm volatile("s_waitcnt vmcnt(0)" ::: "memory"); }
      SBAR; SCHED0;
      const char* P = S[g & 1];
      v8i a[4], b[4];
#pragma unroll
      for (int i = 0; i < 4; ++i) {
        v4i alo = *(const v4i*)(P + arow[i] + offs0);
        v4i ahi = *(const v4i*)(P + arow[i] + offs1);
        a[i] = __builtin_shufflevector(alo, ahi, 0, 1, 2, 3, 4, 5, 6, 7);
        v4i blo = *(const v4i*)(P + brow[i] + offs0);
        v4i bhi = *(const v4i*)(P + brow[i] + offs1);
        b[i] = __builtin_shufflevector(blo, bhi, 0, 1, 2, 3, 4, 5, 6, 7);
      }
      __builtin_amdgcn_s_setprio(1);
      if (kc == 0) {
        f32x4 c0 = {cf0, cf0, cf0, cf0}, c1 = {cf1, cf1, cf1, cf1};
        f32x4 c2 = {cf2, cf2, cf2, cf2}, c3 = {cf3, cf3, cf3, cf3};
#pragma unroll
        for (int mi = 0; mi < 4; ++mi) {
          acc[mi][0] = __builtin_amdgcn_mfma_scale_f32_16x16x128_f8f6f4(a[mi], b[0], c0, 0, 0, 0, SCALE1, 0, SCALE1);
          acc[mi][1] = __builtin_amdgcn_mfma_scale_f32_16x16x128_f8f6f4(a[mi], b[1], c1, 0, 0, 0, SCALE1, 0, SCALE1);
          acc[mi][2] = __builtin_amdgcn_mfma_scale_f32_16x16x128_f8f6f4(a[mi], b[2], c2, 0, 0, 0, SCALE1, 0, SCALE1);
          acc[mi][3] = __builtin_amdgcn_mfma_scale_f32_16x16x128_f8f6f4(a[mi], b[3], c3, 0, 0, 0, SCALE1, 0, SCALE1);
        }
      } else {
#pragma unroll
        for (int mi = 0; mi < 4; ++mi)
#pragma unroll
          for (int fj = 0; fj < 4; ++fj)
            acc[mi][fj] = __builtin_amdgcn_mfma_scale_f32_16x16x128_f8f6f4(a[mi], b[fj], acc[mi][fj], 0, 0, 0, SCALE1, 0, SCALE1);
      }
      __builtin_amdgcn_s_setprio(0);
      SBAR;  // reads of buf g&1 done -> step g+2 may overwrite
    }

    // epilogue: acc IS d~ = c - 2 z.e ; pack (quantized d | code), top-3 insert
#pragma unroll
    for (int mi = 0; mi < 4; ++mi) {
#pragma unroll
      for (int r = 0; r < 4; ++r) {
        float M1 = m1s[mi][r], M2 = m2s[mi][r], M3 = m3s[mi][r];
#pragma unroll
        for (int fj = 0; fj < 4; ++fj) {
          float kf = __uint_as_float((__float_as_uint(acc[mi][fj][r]) & KMASK) |
                                     (unsigned)(codebase + fj * 16));
          float t3 = fminf(M3, fmaxf(M2, kf));
          float t2 = fminf(M2, fmaxf(M1, kf));
          M1 = fminf(M1, kf); M2 = t2; M3 = t3;
        }
        m1s[mi][r] = M1; m2s[mi][r] = M2; m3s[mi][r] = M3;
      }
    }
  }

  // cell = split*32 + wc*16 + col  (64 codes: 16 ct x 4 fj)
  const int cell = split * 32 + wc * 16 + l15;
#pragma unroll
  for (int mi = 0; mi < 4; ++mi) {
#pragma unroll
    for (int r = 0; r < 4; ++r) {
      int token = tb * 128 + wr * 64 + mi * 16 + (lane >> 4) * 4 + r;
      ((float2*)(slot2 + (size_t)token * 256))[cell] = make_float2(m1s[mi][r], m2s[mi][r]);
      slot3[(size_t)token * 128 + cell] = m3s[mi][r];
    }
  }
}

// one wave per token; exact f64 re-rank of margin candidates; writes z_q row.
__global__ void k_select(const float* __restrict__ slot2, const float* __restrict__ slot3,
                         const float* __restrict__ z, const float* __restrict__ w,
                         unsigned int* __restrict__ counts, float* __restrict__ out) {
  const int lane = threadIdx.x & 63;
  const int t = blockIdx.x * 4 + (threadIdx.x >> 6);

  float4 e = *(const float4*)(slot2 + (size_t)t * 256 + lane * 4);  // cells 2l,2l+1 (m1,m2)
  float2 q = *(const float2*)(slot3 + (size_t)t * 128 + lane * 2);  // cells 2l,2l+1 (m3)
  float pk = fminf(e.x, e.z);
#pragma unroll
  for (int m = 1; m < 64; m <<= 1) pk = fminf(pk, __shfl_xor(pk, m));
  const unsigned int mb = __float_as_uint(pk);
  int best = (int)(mb & 0x1FFFu);
  const float thr = __uint_as_float(mb & 0xFFFFE000u) + MARGIN;

  const unsigned int KM = 0xFFFFE000u;
  bool c0 = __uint_as_float(__float_as_uint(e.x) & KM) < thr;
  bool c1 = __uint_as_float(__float_as_uint(e.y) & KM) < thr;
  bool c2 = __uint_as_float(__float_as_uint(e.z) & KM) < thr;
  bool c3 = __uint_as_float(__float_as_uint(e.w) & KM) < thr;
  bool h0 = __uint_as_float(__float_as_uint(q.x) & KM) < thr;  // cell 2l needs full scan
  bool h1 = __uint_as_float(__float_as_uint(q.y) & KM) < thr;  // cell 2l+1
  unsigned long long B0 = __ballot(c0), B1 = __ballot(c1);
  unsigned long long B2 = __ballot(c2), B3 = __ballot(c3);
  unsigned long long H0 = __ballot(h0), H1 = __ballot(h1);
  int nc = __popcll(B0) + __popcll(B1) + __popcll(B2) + __popcll(B3);

  if (nc > 1) {
    const float4* zp = (const float4*)(z + (size_t)t * DIM) + lane * 2;
    float4 za = zp[0], zc = zp[1];
    double bestd = 1e300;
    int besti = NE;

    auto eval = [&](int code) {
      const float4* wp = (const float4*)(w + (size_t)code * DIM) + lane * 2;
      float4 wa = wp[0], wv2 = wp[1];
      double d = (double)wa.x * ((double)wa.x - 2.0 * (double)za.x)
               + (double)wa.y * ((double)wa.y - 2.0 * (double)za.y)
               + (double)wa.z * ((double)wa.z - 2.0 * (double)za.z)
               + (double)wa.w * ((double)wa.w - 2.0 * (double)za.w)
               + (double)wv2.x * ((double)wv2.x - 2.0 * (double)zc.x)
               + (double)wv2.y * ((double)wv2.y - 2.0 * (double)zc.y)
               + (double)wv2.z * ((double)wv2.z - 2.0 * (double)zc.z)
               + (double)wv2.w * ((double)wv2.w - 2.0 * (double)zc.w);
#pragma unroll
      for (int m = 1; m < 64; m <<= 1) d += __shfl_xor(d, m);
      if (d < bestd || (d == bestd && code < besti)) { bestd = d; besti = code; }
    };
    // cell = (split, wc, col): codes sp*2048 + ct*128 + wcc*64 + nf*16 + col
    auto scan_cell = [&](int cid) {
      int sp = cid >> 5, wcc = (cid >> 4) & 1, col = cid & 15;
      int base = sp * 2048 + wcc * 64 + col;
      for (int ctt = 0; ctt < 16; ++ctt)
        for (int nf = 0; nf < 4; ++nf)
          eval(base + ctt * 128 + nf * 16);
    };

    int i0 = (int)(__float_as_uint(e.x) & 0x1FFFu);
    int i1 = (int)(__float_as_uint(e.y) & 0x1FFFu);
    int i2 = (int)(__float_as_uint(e.z) & 0x1FFFu);
    int i3 = (int)(__float_as_uint(e.w) & 0x1FFFu);
    unsigned long long bm;
    bm = __ballot(c0 && !h0); while (bm) { int s = __ffsll(bm) - 1; bm &= bm - 1; eval(__shfl(i0, s)); }
    bm = __ballot(c1 && !h0); while (bm) { int s = __ffsll(bm) - 1; bm &= bm - 1; eval(__shfl(i1, s)); }
    bm = __ballot(c2 && !h1); while (bm) { int s = __ffsll(bm) - 1; bm &= bm - 1; eval(__shfl(i2, s)); }
    bm = __ballot(c3 && !h1); while (bm) { int s = __ffsll(bm) - 1; bm &= bm - 1; eval(__shfl(i3, s)); }
    bm = H0; while (bm) { int s = __ffsll(bm) - 1; bm &= bm - 1; scan_cell(2 * s); }
    bm = H1; while (bm) { int s = __ffsll(bm) - 1; bm &= bm - 1; scan_cell(2 * s + 1); }
    best = besti;
  }
  if (lane == 0) atomicAdd(&counts[best], 1u);
  // write z_q row (gather merged here)
  const float4* wr4 = (const float4*)(w + (size_t)best * DIM);
  float4* o4 = (float4*)(out + (size_t)t * DIM);
  o4[lane]      = wr4[lane];
  o4[lane + 64] = wr4[lane + 64];
}

__global__ void k_perp(const unsigned int* __restrict__ counts, float* __restrict__ out) {
  __shared__ float red[16];
  float s = 0.f;
  for (int k = threadIdx.x; k < NE; k += 1024) {
    float p = (float)counts[k] * (1.0f / (float)NTOK);
    s += p * logf(p + 1e-10f);
  }
#pragma unroll
  for (int m = 1; m < 64; m <<= 1) s += __shfl_xor(s, m);
  int lane = threadIdx.x & 63, wv = threadIdx.x >> 6;
  if (lane == 0) red[wv] = s;
  __syncthreads();
  if (threadIdx.x == 0) {
    float tot = 0.f;
    for (int i = 0; i < 16; ++i) tot += red[i];
    out[(size_t)NTOK * DIM] = expf(-tot);
  }
}

extern "C" void kernel_launch(void* const* d_in, const int* in_sizes, int n_in,
                              void* d_out, int out_size, void* d_ws, size_t ws_size,
                              hipStream_t stream) {
  const float* z = (const float*)d_in[0];
  const float* w = (const float*)d_in[1];
  float* out = (float*)d_out;
  char* ws = (char*)d_ws;

  unsigned char* zb     = (unsigned char*)(ws);
  float*        slot3   = (float*)(ws + 16777216);
  unsigned char* wb     = (unsigned char*)(ws + 33554432);
  float*        cnorm   = (float*)(ws + 41943040);
  float*        slot2   = (float*)(ws + 41975808);
  unsigned int* counts  = (unsigned int*)(ws + 75661312);

  k_prep_z<<<8192, 256, 0, stream>>>(z, (int2*)zb);
  k_prep_w<<<2048, 256, 0, stream>>>(w, (int2*)wb, cnorm);
  k_phase1<<<1024, 256, 0, stream>>>(zb, wb, cnorm, slot2, slot3);
  hipMemsetAsync(counts, 0, NE * sizeof(unsigned int), stream);
  k_select<<<8192, 256, 0, stream>>>(slot2, slot3, z, w, counts, out);
  k_perp<<<1, 1024, 0, stream>>>(counts, out);
}

// Round 18
// 286.719 us; speedup vs baseline: 1.3322x; 1.2203x over previous
//
#include <hip/hip_runtime.h>
#include <stdint.h>

// VectorQuantizer: z[32768,512] f32, weight[8192,512] f32 ->
//   out[0 .. 32768*512) = z_q = weight[argmin_k ||z-e_k||^2]  (exact fp32 rows)
//   out[32768*512]      = perplexity
//
// Pipeline (r15 consolidated best + fused prep launch):
//  1) k_prep: fused e4m3(-2z) + e4m3(w) + exact f32 row norms c_k
//  2) k_phase1: 128x128 tile, 4 waves, mfma_scale_f32_16x16x128_f8f6f4
//     (uniform scale 2^0). A AND B staged per K-step via global_load_lds,
//     dbuf 2x32KB (VGPR 108 -> 2 blocks/CU; the empirically-required TLP),
//     counted vmcnt(8), 2 raw barriers/step, setprio, ROLLED kc loop
//     (unrolling raises VGPR and kills the 2nd block - r17).
//     acc init = ||e||^2 via C operand -> d~ = c - 2 z.e. Per token: TOP-3
//     packed keys (quantized d | 13-bit code) per 128 cells -> slot2+slot3.
//  3) k_select: global min; MARGIN=16 candidates (m1/m2 direct, full 64-code
//     rescan only if m3 in margin) re-ranked with exact f64 dots; histogram;
//     writes z_q row directly.   4) k_perp: perplexity
//
// ws layout (bytes): zb@0 16MB | slot3@16777216 16MB | wb@33554432 4MB |
//   cnorm@41943040 32KB | slot2@41975808 32MB | counts@75661312 32KB

#define NTOK 32768
#define NE   8192
#define DIM  512
#define MARGIN 16.0f

typedef __attribute__((ext_vector_type(8))) int   v8i;
typedef __attribute__((ext_vector_type(4))) int   v4i;
typedef __attribute__((ext_vector_type(4))) float f32x4;

#define SBAR   __builtin_amdgcn_s_barrier()
#define SCHED0 __builtin_amdgcn_sched_barrier(0)
#define SCALE1 0x7F7F7F7F  // e8m0 biased-127 = 2^0 in every byte

__device__ __forceinline__ void gl_lds16(const void* g, void* l) {
  __builtin_amdgcn_global_load_lds(
      (const __attribute__((address_space(1))) void*)g,
      (__attribute__((address_space(3))) void*)l, 16, 0, 0);
}

__device__ __forceinline__ int pk8(float a, float b, float c, float d) {
  int r = __builtin_amdgcn_cvt_pk_fp8_f32(a, b, 0, false);
  return __builtin_amdgcn_cvt_pk_fp8_f32(c, d, r, true);
}

// fused prep: blocks [0,8192) -> e4m3(-2z); blocks [8192,10240) -> e4m3(w)+norms
__global__ void k_prep(const float* __restrict__ z, const float* __restrict__ w,
                       int2* __restrict__ zb, int2* __restrict__ wb,
                       float* __restrict__ cnorm) {
  if (blockIdx.x < 8192) {
    int i = blockIdx.x * 256 + threadIdx.x;  // one thread per 8 floats, row-major
    const float4* zp = (const float4*)z + (size_t)i * 2;
    float4 a = zp[0], b = zp[1];
    int2 o;  // e4m3(-2z)
    o.x = pk8(-2.f * a.x, -2.f * a.y, -2.f * a.z, -2.f * a.w);
    o.y = pk8(-2.f * b.x, -2.f * b.y, -2.f * b.z, -2.f * b.w);
    zb[i] = o;
  } else {
    int row  = (blockIdx.x - 8192) * 4 + (threadIdx.x >> 6);  // one wave per code row
    int lane = threadIdx.x & 63;
    const float4* wp = (const float4*)(w + (size_t)row * DIM) + lane * 2;
    float4 a = wp[0], b = wp[1];
    int2 o;
    o.x = pk8(a.x, a.y, a.z, a.w);
    o.y = pk8(b.x, b.y, b.z, b.w);
    wb[(size_t)row * 64 + lane] = o;
    float s = a.x * a.x + a.y * a.y + a.z * a.z + a.w * a.w
            + b.x * b.x + b.y * b.y + b.z * b.z + b.w * b.w;
#pragma unroll
    for (int m = 1; m < 64; m <<= 1) s += __shfl_xor(s, m);
    if (lane == 0) cnorm[row] = s;
  }
}

// 256 thr = 4 waves (wr,wc 2x2), tile 128 tok x 128 codes, wave 64x64.
// K-step 128 fp8: rows 128B (8 x 16B slots), slot-XOR swizzle c^(row&7).
// dbuf 2x32KB; 8 gl_lds/wave/step (4 A + 4 B); vmcnt(8); 64 K-steps.
// grid 1024 = 256 tb x 4 splits, XCD-chunked bijective swizzle.
__global__ void __launch_bounds__(256) k_phase1(
    const unsigned char* __restrict__ zb, const unsigned char* __restrict__ wb,
    const float* __restrict__ cnorm, float* __restrict__ slot2,
    float* __restrict__ slot3) {
  __shared__ char S[2][32768];  // [buf][A: 128 rows x 128B | B: 128 rows x 128B]

  const int tid  = threadIdx.x;
  const int lane = tid & 63;
  const int wv   = tid >> 6;
  const int wr   = wv >> 1;
  const int wc   = wv & 1;
  const int swzb  = (blockIdx.x & 7) * 128 + (blockIdx.x >> 3);
  const int split = swzb >> 8;   // 0..3
  const int tb    = swzb & 255;  // 0..255
  const int l15  = lane & 15;

  // staging: lane l -> dest row l>>3, slot l&7; swizzled store slot = c^(row&7)
  // => pre-swizzled source slot = (l&7) ^ ((l>>3)&7).
  const int srcsw = (((lane & 7) ^ ((lane >> 3) & 7)) << 4);
  const unsigned char* zsA = zb + (size_t)(tb * 128 + wv * 32 + (lane >> 3)) * 512 + srcsw;
  const unsigned char* zsB = wb + (size_t)(split * 2048 + wv * 32 + (lane >> 3)) * 512 + srcsw;

  // frag reads: lane wants slots {2g, 2g+1} (g = lane>>4) of row base+l15;
  // stored slot = want ^ (row&7), row&7 == lane&7 (bases are 0 mod 16).
  const int offs0 = ((((lane >> 4) * 2) ^ (lane & 7)) << 4);
  const int offs1 = ((((lane >> 4) * 2 + 1) ^ (lane & 7)) << 4);
  int arow[4], brow[4];
#pragma unroll
  for (int i = 0; i < 4; ++i) {
    arow[i] = (wr * 64 + i * 16 + l15) * 128;
    brow[i] = 16384 + (wc * 64 + i * 16 + l15) * 128;
  }

  const float BIG = 3.0e38f;
  float m1s[4][4], m2s[4][4], m3s[4][4];
#pragma unroll
  for (int mi = 0; mi < 4; ++mi)
#pragma unroll
    for (int r = 0; r < 4; ++r) { m1s[mi][r] = BIG; m2s[mi][r] = BIG; m3s[mi][r] = BIG; }

  const unsigned int KMASK = 0xFFFFE000u;

  // stage K-step g (= ct*4+kc) into buf g&1: A 4 + B 4 gl_lds per wave
  auto stage = [&](int g) {
    char* DA = &S[g & 1][wv * 4096];
    const unsigned char* ga = zsA + ((g & 3) << 7);
#pragma unroll
    for (int r = 0; r < 4; ++r) gl_lds16(ga + r * 4096, DA + r * 1024);
    char* DB = &S[g & 1][16384 + wv * 4096];
    const unsigned char* gb = zsB + ((size_t)(g >> 2) << 16) + ((g & 3) << 7);
#pragma unroll
    for (int r = 0; r < 4; ++r) gl_lds16(gb + r * 4096, DB + r * 1024);
  };

  stage(0);
  __syncthreads();  // drains prologue; queue clean

  for (int ct = 0; ct < 16; ++ct) {
    const int codebase = split * 2048 + ct * 128 + wc * 64 + l15;
    // cf loads are older than stage(g+1) -> drained by kc=0's vmcnt(8)
    float cf0 = cnorm[codebase + 0];
    float cf1 = cnorm[codebase + 16];
    float cf2 = cnorm[codebase + 32];
    float cf3 = cnorm[codebase + 48];
    f32x4 acc[4][4];

#pragma unroll 1
    for (int kc = 0; kc < 4; ++kc) {
      const int g = ct * 4 + kc;
      if (g < 63) { stage(g + 1); asm volatile("s_waitcnt vmcnt(8)" ::: "memory"); }
      else        { asm volatile("s_waitcnt vmcnt(0)" ::: "memory"); }
      SBAR; SCHED0;
      const char* P = S[g & 1];
      v8i a[4], b[4];
#pragma unroll
      for (int i = 0; i < 4; ++i) {
        v4i alo = *(const v4i*)(P + arow[i] + offs0);
        v4i ahi = *(const v4i*)(P + arow[i] + offs1);
        a[i] = __builtin_shufflevector(alo, ahi, 0, 1, 2, 3, 4, 5, 6, 7);
        v4i blo = *(const v4i*)(P + brow[i] + offs0);
        v4i bhi = *(const v4i*)(P + brow[i] + offs1);
        b[i] = __builtin_shufflevector(blo, bhi, 0, 1, 2, 3, 4, 5, 6, 7);
      }
      __builtin_amdgcn_s_setprio(1);
      if (kc == 0) {
        f32x4 c0 = {cf0, cf0, cf0, cf0}, c1 = {cf1, cf1, cf1, cf1};
        f32x4 c2 = {cf2, cf2, cf2, cf2}, c3 = {cf3, cf3, cf3, cf3};
#pragma unroll
        for (int mi = 0; mi < 4; ++mi) {
          acc[mi][0] = __builtin_amdgcn_mfma_scale_f32_16x16x128_f8f6f4(a[mi], b[0], c0, 0, 0, 0, SCALE1, 0, SCALE1);
          acc[mi][1] = __builtin_amdgcn_mfma_scale_f32_16x16x128_f8f6f4(a[mi], b[1], c1, 0, 0, 0, SCALE1, 0, SCALE1);
          acc[mi][2] = __builtin_amdgcn_mfma_scale_f32_16x16x128_f8f6f4(a[mi], b[2], c2, 0, 0, 0, SCALE1, 0, SCALE1);
          acc[mi][3] = __builtin_amdgcn_mfma_scale_f32_16x16x128_f8f6f4(a[mi], b[3], c3, 0, 0, 0, SCALE1, 0, SCALE1);
        }
      } else {
#pragma unroll
        for (int mi = 0; mi < 4; ++mi)
#pragma unroll
          for (int fj = 0; fj < 4; ++fj)
            acc[mi][fj] = __builtin_amdgcn_mfma_scale_f32_16x16x128_f8f6f4(a[mi], b[fj], acc[mi][fj], 0, 0, 0, SCALE1, 0, SCALE1);
      }
      __builtin_amdgcn_s_setprio(0);
      SBAR;  // reads of buf g&1 done -> step g+2 may overwrite
    }

    // epilogue: acc IS d~ = c - 2 z.e ; pack (quantized d | code), top-3 insert
#pragma unroll
    for (int mi = 0; mi < 4; ++mi) {
#pragma unroll
      for (int r = 0; r < 4; ++r) {
        float M1 = m1s[mi][r], M2 = m2s[mi][r], M3 = m3s[mi][r];
#pragma unroll
        for (int fj = 0; fj < 4; ++fj) {
          float kf = __uint_as_float((__float_as_uint(acc[mi][fj][r]) & KMASK) |
                                     (unsigned)(codebase + fj * 16));
          float t3 = fminf(M3, fmaxf(M2, kf));
          float t2 = fminf(M2, fmaxf(M1, kf));
          M1 = fminf(M1, kf); M2 = t2; M3 = t3;
        }
        m1s[mi][r] = M1; m2s[mi][r] = M2; m3s[mi][r] = M3;
      }
    }
  }

  // cell = split*32 + wc*16 + col  (64 codes: 16 ct x 4 fj)
  const int cell = split * 32 + wc * 16 + l15;
#pragma unroll
  for (int mi = 0; mi < 4; ++mi) {
#pragma unroll
    for (int r = 0; r < 4; ++r) {
      int token = tb * 128 + wr * 64 + mi * 16 + (lane >> 4) * 4 + r;
      ((float2*)(slot2 + (size_t)token * 256))[cell] = make_float2(m1s[mi][r], m2s[mi][r]);
      slot3[(size_t)token * 128 + cell] = m3s[mi][r];
    }
  }
}

// one wave per token; exact f64 re-rank of margin candidates; writes z_q row.
__global__ void k_select(const float* __restrict__ slot2, const float* __restrict__ slot3,
                         const float* __restrict__ z, const float* __restrict__ w,
                         unsigned int* __restrict__ counts, float* __restrict__ out) {
  const int lane = threadIdx.x & 63;
  const int t = blockIdx.x * 4 + (threadIdx.x >> 6);

  float4 e = *(const float4*)(slot2 + (size_t)t * 256 + lane * 4);  // cells 2l,2l+1 (m1,m2)
  float2 q = *(const float2*)(slot3 + (size_t)t * 128 + lane * 2);  // cells 2l,2l+1 (m3)
  float pk = fminf(e.x, e.z);
#pragma unroll
  for (int m = 1; m < 64; m <<= 1) pk = fminf(pk, __shfl_xor(pk, m));
  const unsigned int mb = __float_as_uint(pk);
  int best = (int)(mb & 0x1FFFu);
  const float thr = __uint_as_float(mb & 0xFFFFE000u) + MARGIN;

  const unsigned int KM = 0xFFFFE000u;
  bool c0 = __uint_as_float(__float_as_uint(e.x) & KM) < thr;
  bool c1 = __uint_as_float(__float_as_uint(e.y) & KM) < thr;
  bool c2 = __uint_as_float(__float_as_uint(e.z) & KM) < thr;
  bool c3 = __uint_as_float(__float_as_uint(e.w) & KM) < thr;
  bool h0 = __uint_as_float(__float_as_uint(q.x) & KM) < thr;  // cell 2l needs full scan
  bool h1 = __uint_as_float(__float_as_uint(q.y) & KM) < thr;  // cell 2l+1
  unsigned long long B0 = __ballot(c0), B1 = __ballot(c1);
  unsigned long long B2 = __ballot(c2), B3 = __ballot(c3);
  unsigned long long H0 = __ballot(h0), H1 = __ballot(h1);
  int nc = __popcll(B0) + __popcll(B1) + __popcll(B2) + __popcll(B3);

  if (nc > 1) {
    const float4* zp = (const float4*)(z + (size_t)t * DIM) + lane * 2;
    float4 za = zp[0], zc = zp[1];
    double bestd = 1e300;
    int besti = NE;

    auto eval = [&](int code) {
      const float4* wp = (const float4*)(w + (size_t)code * DIM) + lane * 2;
      float4 wa = wp[0], wv2 = wp[1];
      double d = (double)wa.x * ((double)wa.x - 2.0 * (double)za.x)
               + (double)wa.y * ((double)wa.y - 2.0 * (double)za.y)
               + (double)wa.z * ((double)wa.z - 2.0 * (double)za.z)
               + (double)wa.w * ((double)wa.w - 2.0 * (double)za.w)
               + (double)wv2.x * ((double)wv2.x - 2.0 * (double)zc.x)
               + (double)wv2.y * ((double)wv2.y - 2.0 * (double)zc.y)
               + (double)wv2.z * ((double)wv2.z - 2.0 * (double)zc.z)
               + (double)wv2.w * ((double)wv2.w - 2.0 * (double)zc.w);
#pragma unroll
      for (int m = 1; m < 64; m <<= 1) d += __shfl_xor(d, m);
      if (d < bestd || (d == bestd && code < besti)) { bestd = d; besti = code; }
    };
    // cell = (split, wc, col): codes sp*2048 + ct*128 + wcc*64 + nf*16 + col
    auto scan_cell = [&](int cid) {
      int sp = cid >> 5, wcc = (cid >> 4) & 1, col = cid & 15;
      int base = sp * 2048 + wcc * 64 + col;
      for (int ctt = 0; ctt < 16; ++ctt)
        for (int nf = 0; nf < 4; ++nf)
          eval(base + ctt * 128 + nf * 16);
    };

    int i0 = (int)(__float_as_uint(e.x) & 0x1FFFu);
    int i1 = (int)(__float_as_uint(e.y) & 0x1FFFu);
    int i2 = (int)(__float_as_uint(e.z) & 0x1FFFu);
    int i3 = (int)(__float_as_uint(e.w) & 0x1FFFu);
    unsigned long long bm;
    bm = __ballot(c0 && !h0); while (bm) { int s = __ffsll(bm) - 1; bm &= bm - 1; eval(__shfl(i0, s)); }
    bm = __ballot(c1 && !h0); while (bm) { int s = __ffsll(bm) - 1; bm &= bm - 1; eval(__shfl(i1, s)); }
    bm = __ballot(c2 && !h1); while (bm) { int s = __ffsll(bm) - 1; bm &= bm - 1; eval(__shfl(i2, s)); }
    bm = __ballot(c3 && !h1); while (bm) { int s = __ffsll(bm) - 1; bm &= bm - 1; eval(__shfl(i3, s)); }
    bm = H0; while (bm) { int s = __ffsll(bm) - 1; bm &= bm - 1; scan_cell(2 * s); }
    bm = H1; while (bm) { int s = __ffsll(bm) - 1; bm &= bm - 1; scan_cell(2 * s + 1); }
    best = besti;
  }
  if (lane == 0) atomicAdd(&counts[best], 1u);
  // write z_q row (gather merged here)
  const float4* wr4 = (const float4*)(w + (size_t)best * DIM);
  float4* o4 = (float4*)(out + (size_t)t * DIM);
  o4[lane]      = wr4[lane];
  o4[lane + 64] = wr4[lane + 64];
}

__global__ void k_perp(const unsigned int* __restrict__ counts, float* __restrict__ out) {
  __shared__ float red[16];
  float s = 0.f;
  for (int k = threadIdx.x; k < NE; k += 1024) {
    float p = (float)counts[k] * (1.0f / (float)NTOK);
    s += p * logf(p + 1e-10f);
  }
#pragma unroll
  for (int m = 1; m < 64; m <<= 1) s += __shfl_xor(s, m);
  int lane = threadIdx.x & 63, wv = threadIdx.x >> 6;
  if (lane == 0) red[wv] = s;
  __syncthreads();
  if (threadIdx.x == 0) {
    float tot = 0.f;
    for (int i = 0; i < 16; ++i) tot += red[i];
    out[(size_t)NTOK * DIM] = expf(-tot);
  }
}

extern "C" void kernel_launch(void* const* d_in, const int* in_sizes, int n_in,
                              void* d_out, int out_size, void* d_ws, size_t ws_size,
                              hipStream_t stream) {
  const float* z = (const float*)d_in[0];
  const float* w = (const float*)d_in[1];
  float* out = (float*)d_out;
  char* ws = (char*)d_ws;

  unsigned char* zb     = (unsigned char*)(ws);
  float*        slot3   = (float*)(ws + 16777216);
  unsigned char* wb     = (unsigned char*)(ws + 33554432);
  float*        cnorm   = (float*)(ws + 41943040);
  float*        slot2   = (float*)(ws + 41975808);
  unsigned int* counts  = (unsigned int*)(ws + 75661312);

  k_prep<<<10240, 256, 0, stream>>>(z, w, (int2*)zb, (int2*)wb, cnorm);
  k_phase1<<<1024, 256, 0, stream>>>(zb, wb, cnorm, slot2, slot3);
  hipMemsetAsync(counts, 0, NE * sizeof(unsigned int), stream);
  k_select<<<8192, 256, 0, stream>>>(slot2, slot3, z, w, counts, out);
  k_perp<<<1, 1024, 0, stream>>>(counts, out);
}

// Round 19
// 277.694 us; speedup vs baseline: 1.3755x; 1.0325x over previous
//
#include <hip/hip_runtime.h>
#include <stdint.h>

// VectorQuantizer: z[32768,512] f32, weight[8192,512] f32 ->
//   out[0 .. 32768*512) = z_q = weight[argmin_k ||z-e_k||^2]  (exact fp32 rows)
//   out[32768*512]      = perplexity
//
// FINAL (r15 consolidated best, re-submitted):
//  1) k_prep_z: e4m3(-2z) row-major; k_prep_w: e4m3(w) + exact f32 norms c_k
//  2) k_phase1: 128x128 tile, 4 waves, mfma_scale_f32_16x16x128_f8f6f4
//     (uniform scale 2^0). A AND B staged per K-step via global_load_lds
//     (keeps B L2-resident; FETCH ~186MB), dbuf 2x32KB, VGPR 108 ->
//     2 blocks/CU (the empirically-required TLP), counted vmcnt(8),
//     2 raw barriers/step, setprio, ROLLED kc loop (unroll raises VGPR and
//     kills the 2nd block). acc init = ||e||^2 via C operand -> d~ = c-2z.e.
//     Per token: TOP-3 packed keys (quantized d | 13-bit code) per 128 cells
//     (cell=(split,wc,col); 64 codes = 16ct x 4fj) -> slot2 + slot3.
//  3) k_select: global min; MARGIN=16 candidates (m1/m2 direct, full 64-code
//     rescan only if m3 in margin) re-ranked with exact f64 dots; histogram;
//     writes z_q row directly (gather merged).
//  4) k_perp: perplexity
//
// ws layout (bytes): zb@0 16MB | slot3@16777216 16MB | wb@33554432 4MB |
//   cnorm@41943040 32KB | slot2@41975808 32MB | counts@75661312 32KB

#define NTOK 32768
#define NE   8192
#define DIM  512
#define MARGIN 16.0f

typedef __attribute__((ext_vector_type(8))) int   v8i;
typedef __attribute__((ext_vector_type(4))) int   v4i;
typedef __attribute__((ext_vector_type(4))) float f32x4;

#define SBAR   __builtin_amdgcn_s_barrier()
#define SCHED0 __builtin_amdgcn_sched_barrier(0)
#define SCALE1 0x7F7F7F7F  // e8m0 biased-127 = 2^0 in every byte

__device__ __forceinline__ void gl_lds16(const void* g, void* l) {
  __builtin_amdgcn_global_load_lds(
      (const __attribute__((address_space(1))) void*)g,
      (__attribute__((address_space(3))) void*)l, 16, 0, 0);
}

__device__ __forceinline__ int pk8(float a, float b, float c, float d) {
  int r = __builtin_amdgcn_cvt_pk_fp8_f32(a, b, 0, false);
  return __builtin_amdgcn_cvt_pk_fp8_f32(c, d, r, true);
}

__global__ void k_prep_z(const float* __restrict__ z, int2* __restrict__ zb) {
  int i = blockIdx.x * 256 + threadIdx.x;  // one thread per 8 floats, row-major
  const float4* zp = (const float4*)z + (size_t)i * 2;
  float4 a = zp[0], b = zp[1];
  int2 o;  // e4m3(-2z)
  o.x = pk8(-2.f * a.x, -2.f * a.y, -2.f * a.z, -2.f * a.w);
  o.y = pk8(-2.f * b.x, -2.f * b.y, -2.f * b.z, -2.f * b.w);
  zb[i] = o;
}

__global__ void k_prep_w(const float* __restrict__ w, int2* __restrict__ wb,
                         float* __restrict__ cnorm) {
  int row  = blockIdx.x * 4 + (threadIdx.x >> 6);  // one wave per code row
  int lane = threadIdx.x & 63;
  const float4* wp = (const float4*)(w + (size_t)row * DIM) + lane * 2;
  float4 a = wp[0], b = wp[1];
  int2 o;
  o.x = pk8(a.x, a.y, a.z, a.w);
  o.y = pk8(b.x, b.y, b.z, b.w);
  wb[(size_t)row * 64 + lane] = o;
  float s = a.x * a.x + a.y * a.y + a.z * a.z + a.w * a.w
          + b.x * b.x + b.y * b.y + b.z * b.z + b.w * b.w;
#pragma unroll
  for (int m = 1; m < 64; m <<= 1) s += __shfl_xor(s, m);
  if (lane == 0) cnorm[row] = s;
}

// 256 thr = 4 waves (wr,wc 2x2), tile 128 tok x 128 codes, wave 64x64.
// K-step 128 fp8: rows 128B (8 x 16B slots), slot-XOR swizzle c^(row&7).
// dbuf 2x32KB; 8 gl_lds/wave/step (4 A + 4 B); vmcnt(8); 64 K-steps.
// grid 1024 = 256 tb x 4 splits, XCD-chunked bijective swizzle.
__global__ void __launch_bounds__(256) k_phase1(
    const unsigned char* __restrict__ zb, const unsigned char* __restrict__ wb,
    const float* __restrict__ cnorm, float* __restrict__ slot2,
    float* __restrict__ slot3) {
  __shared__ char S[2][32768];  // [buf][A: 128 rows x 128B | B: 128 rows x 128B]

  const int tid  = threadIdx.x;
  const int lane = tid & 63;
  const int wv   = tid >> 6;
  const int wr   = wv >> 1;
  const int wc   = wv & 1;
  const int swzb  = (blockIdx.x & 7) * 128 + (blockIdx.x >> 3);
  const int split = swzb >> 8;   // 0..3
  const int tb    = swzb & 255;  // 0..255
  const int l15  = lane & 15;

  // staging: lane l -> dest row l>>3, slot l&7; swizzled store slot = c^(row&7)
  // => pre-swizzled source slot = (l&7) ^ ((l>>3)&7).
  const int srcsw = (((lane & 7) ^ ((lane >> 3) & 7)) << 4);
  const unsigned char* zsA = zb + (size_t)(tb * 128 + wv * 32 + (lane >> 3)) * 512 + srcsw;
  const unsigned char* zsB = wb + (size_t)(split * 2048 + wv * 32 + (lane >> 3)) * 512 + srcsw;

  // frag reads: lane wants slots {2g, 2g+1} (g = lane>>4) of row base+l15;
  // stored slot = want ^ (row&7), row&7 == lane&7 (bases are 0 mod 16).
  const int offs0 = ((((lane >> 4) * 2) ^ (lane & 7)) << 4);
  const int offs1 = ((((lane >> 4) * 2 + 1) ^ (lane & 7)) << 4);
  int arow[4], brow[4];
#pragma unroll
  for (int i = 0; i < 4; ++i) {
    arow[i] = (wr * 64 + i * 16 + l15) * 128;
    brow[i] = 16384 + (wc * 64 + i * 16 + l15) * 128;
  }

  const float BIG = 3.0e38f;
  float m1s[4][4], m2s[4][4], m3s[4][4];
#pragma unroll
  for (int mi = 0; mi < 4; ++mi)
#pragma unroll
    for (int r = 0; r < 4; ++r) { m1s[mi][r] = BIG; m2s[mi][r] = BIG; m3s[mi][r] = BIG; }

  const unsigned int KMASK = 0xFFFFE000u;

  // stage K-step g (= ct*4+kc) into buf g&1: A 4 + B 4 gl_lds per wave
  auto stage = [&](int g) {
    char* DA = &S[g & 1][wv * 4096];
    const unsigned char* ga = zsA + ((g & 3) << 7);
#pragma unroll
    for (int r = 0; r < 4; ++r) gl_lds16(ga + r * 4096, DA + r * 1024);
    char* DB = &S[g & 1][16384 + wv * 4096];
    const unsigned char* gb = zsB + ((size_t)(g >> 2) << 16) + ((g & 3) << 7);
#pragma unroll
    for (int r = 0; r < 4; ++r) gl_lds16(gb + r * 4096, DB + r * 1024);
  };

  stage(0);
  __syncthreads();  // drains prologue; queue clean

  for (int ct = 0; ct < 16; ++ct) {
    const int codebase = split * 2048 + ct * 128 + wc * 64 + l15;
    // cf loads are older than stage(g+1) -> drained by kc=0's vmcnt(8)
    float cf0 = cnorm[codebase + 0];
    float cf1 = cnorm[codebase + 16];
    float cf2 = cnorm[codebase + 32];
    float cf3 = cnorm[codebase + 48];
    f32x4 acc[4][4];

#pragma unroll 1
    for (int kc = 0; kc < 4; ++kc) {
      const int g = ct * 4 + kc;
      if (g < 63) { stage(g + 1); asm volatile("s_waitcnt vmcnt(8)" ::: "memory"); }
      else        { asm volatile("s_waitcnt vmcnt(0)" ::: "memory"); }
      SBAR; SCHED0;
      const char* P = S[g & 1];
      v8i a[4], b[4];
#pragma unroll
      for (int i = 0; i < 4; ++i) {
        v4i alo = *(const v4i*)(P + arow[i] + offs0);
        v4i ahi = *(const v4i*)(P + arow[i] + offs1);
        a[i] = __builtin_shufflevector(alo, ahi, 0, 1, 2, 3, 4, 5, 6, 7);
        v4i blo = *(const v4i*)(P + brow[i] + offs0);
        v4i bhi = *(const v4i*)(P + brow[i] + offs1);
        b[i] = __builtin_shufflevector(blo, bhi, 0, 1, 2, 3, 4, 5, 6, 7);
      }
      __builtin_amdgcn_s_setprio(1);
      if (kc == 0) {
        f32x4 c0 = {cf0, cf0, cf0, cf0}, c1 = {cf1, cf1, cf1, cf1};
        f32x4 c2 = {cf2, cf2, cf2, cf2}, c3 = {cf3, cf3, cf3, cf3};
#pragma unroll
        for (int mi = 0; mi < 4; ++mi) {
          acc[mi][0] = __builtin_amdgcn_mfma_scale_f32_16x16x128_f8f6f4(a[mi], b[0], c0, 0, 0, 0, SCALE1, 0, SCALE1);
          acc[mi][1] = __builtin_amdgcn_mfma_scale_f32_16x16x128_f8f6f4(a[mi], b[1], c1, 0, 0, 0, SCALE1, 0, SCALE1);
          acc[mi][2] = __builtin_amdgcn_mfma_scale_f32_16x16x128_f8f6f4(a[mi], b[2], c2, 0, 0, 0, SCALE1, 0, SCALE1);
          acc[mi][3] = __builtin_amdgcn_mfma_scale_f32_16x16x128_f8f6f4(a[mi], b[3], c3, 0, 0, 0, SCALE1, 0, SCALE1);
        }
      } else {
#pragma unroll
        for (int mi = 0; mi < 4; ++mi)
#pragma unroll
          for (int fj = 0; fj < 4; ++fj)
            acc[mi][fj] = __builtin_amdgcn_mfma_scale_f32_16x16x128_f8f6f4(a[mi], b[fj], acc[mi][fj], 0, 0, 0, SCALE1, 0, SCALE1);
      }
      __builtin_amdgcn_s_setprio(0);
      SBAR;  // reads of buf g&1 done -> step g+2 may overwrite
    }

    // epilogue: acc IS d~ = c - 2 z.e ; pack (quantized d | code), top-3 insert
#pragma unroll
    for (int mi = 0; mi < 4; ++mi) {
#pragma unroll
      for (int r = 0; r < 4; ++r) {
        float M1 = m1s[mi][r], M2 = m2s[mi][r], M3 = m3s[mi][r];
#pragma unroll
        for (int fj = 0; fj < 4; ++fj) {
          float kf = __uint_as_float((__float_as_uint(acc[mi][fj][r]) & KMASK) |
                                     (unsigned)(codebase + fj * 16));
          float t3 = fminf(M3, fmaxf(M2, kf));
          float t2 = fminf(M2, fmaxf(M1, kf));
          M1 = fminf(M1, kf); M2 = t2; M3 = t3;
        }
        m1s[mi][r] = M1; m2s[mi][r] = M2; m3s[mi][r] = M3;
      }
    }
  }

  // cell = split*32 + wc*16 + col  (64 codes: 16 ct x 4 fj)
  const int cell = split * 32 + wc * 16 + l15;
#pragma unroll
  for (int mi = 0; mi < 4; ++mi) {
#pragma unroll
    for (int r = 0; r < 4; ++r) {
      int token = tb * 128 + wr * 64 + mi * 16 + (lane >> 4) * 4 + r;
      ((float2*)(slot2 + (size_t)token * 256))[cell] = make_float2(m1s[mi][r], m2s[mi][r]);
      slot3[(size_t)token * 128 + cell] = m3s[mi][r];
    }
  }
}

// one wave per token; exact f64 re-rank of margin candidates; writes z_q row.
__global__ void k_select(const float* __restrict__ slot2, const float* __restrict__ slot3,
                         const float* __restrict__ z, const float* __restrict__ w,
                         unsigned int* __restrict__ counts, float* __restrict__ out) {
  const int lane = threadIdx.x & 63;
  const int t = blockIdx.x * 4 + (threadIdx.x >> 6);

  float4 e = *(const float4*)(slot2 + (size_t)t * 256 + lane * 4);  // cells 2l,2l+1 (m1,m2)
  float2 q = *(const float2*)(slot3 + (size_t)t * 128 + lane * 2);  // cells 2l,2l+1 (m3)
  float pk = fminf(e.x, e.z);
#pragma unroll
  for (int m = 1; m < 64; m <<= 1) pk = fminf(pk, __shfl_xor(pk, m));
  const unsigned int mb = __float_as_uint(pk);
  int best = (int)(mb & 0x1FFFu);
  const float thr = __uint_as_float(mb & 0xFFFFE000u) + MARGIN;

  const unsigned int KM = 0xFFFFE000u;
  bool c0 = __uint_as_float(__float_as_uint(e.x) & KM) < thr;
  bool c1 = __uint_as_float(__float_as_uint(e.y) & KM) < thr;
  bool c2 = __uint_as_float(__float_as_uint(e.z) & KM) < thr;
  bool c3 = __uint_as_float(__float_as_uint(e.w) & KM) < thr;
  bool h0 = __uint_as_float(__float_as_uint(q.x) & KM) < thr;  // cell 2l needs full scan
  bool h1 = __uint_as_float(__float_as_uint(q.y) & KM) < thr;  // cell 2l+1
  unsigned long long B0 = __ballot(c0), B1 = __ballot(c1);
  unsigned long long B2 = __ballot(c2), B3 = __ballot(c3);
  unsigned long long H0 = __ballot(h0), H1 = __ballot(h1);
  int nc = __popcll(B0) + __popcll(B1) + __popcll(B2) + __popcll(B3);

  if (nc > 1) {
    const float4* zp = (const float4*)(z + (size_t)t * DIM) + lane * 2;
    float4 za = zp[0], zc = zp[1];
    double bestd = 1e300;
    int besti = NE;

    auto eval = [&](int code) {
      const float4* wp = (const float4*)(w + (size_t)code * DIM) + lane * 2;
      float4 wa = wp[0], wv2 = wp[1];
      double d = (double)wa.x * ((double)wa.x - 2.0 * (double)za.x)
               + (double)wa.y * ((double)wa.y - 2.0 * (double)za.y)
               + (double)wa.z * ((double)wa.z - 2.0 * (double)za.z)
               + (double)wa.w * ((double)wa.w - 2.0 * (double)za.w)
               + (double)wv2.x * ((double)wv2.x - 2.0 * (double)zc.x)
               + (double)wv2.y * ((double)wv2.y - 2.0 * (double)zc.y)
               + (double)wv2.z * ((double)wv2.z - 2.0 * (double)zc.z)
               + (double)wv2.w * ((double)wv2.w - 2.0 * (double)zc.w);
#pragma unroll
      for (int m = 1; m < 64; m <<= 1) d += __shfl_xor(d, m);
      if (d < bestd || (d == bestd && code < besti)) { bestd = d; besti = code; }
    };
    // cell = (split, wc, col): codes sp*2048 + ct*128 + wcc*64 + nf*16 + col
    auto scan_cell = [&](int cid) {
      int sp = cid >> 5, wcc = (cid >> 4) & 1, col = cid & 15;
      int base = sp * 2048 + wcc * 64 + col;
      for (int ctt = 0; ctt < 16; ++ctt)
        for (int nf = 0; nf < 4; ++nf)
          eval(base + ctt * 128 + nf * 16);
    };

    int i0 = (int)(__float_as_uint(e.x) & 0x1FFFu);
    int i1 = (int)(__float_as_uint(e.y) & 0x1FFFu);
    int i2 = (int)(__float_as_uint(e.z) & 0x1FFFu);
    int i3 = (int)(__float_as_uint(e.w) & 0x1FFFu);
    unsigned long long bm;
    bm = __ballot(c0 && !h0); while (bm) { int s = __ffsll(bm) - 1; bm &= bm - 1; eval(__shfl(i0, s)); }
    bm = __ballot(c1 && !h0); while (bm) { int s = __ffsll(bm) - 1; bm &= bm - 1; eval(__shfl(i1, s)); }
    bm = __ballot(c2 && !h1); while (bm) { int s = __ffsll(bm) - 1; bm &= bm - 1; eval(__shfl(i2, s)); }
    bm = __ballot(c3 && !h1); while (bm) { int s = __ffsll(bm) - 1; bm &= bm - 1; eval(__shfl(i3, s)); }
    bm = H0; while (bm) { int s = __ffsll(bm) - 1; bm &= bm - 1; scan_cell(2 * s); }
    bm = H1; while (bm) { int s = __ffsll(bm) - 1; bm &= bm - 1; scan_cell(2 * s + 1); }
    best = besti;
  }
  if (lane == 0) atomicAdd(&counts[best], 1u);
  // write z_q row (gather merged here)
  const float4* wr4 = (const float4*)(w + (size_t)best * DIM);
  float4* o4 = (float4*)(out + (size_t)t * DIM);
  o4[lane]      = wr4[lane];
  o4[lane + 64] = wr4[lane + 64];
}

__global__ void k_perp(const unsigned int* __restrict__ counts, float* __restrict__ out) {
  __shared__ float red[16];
  float s = 0.f;
  for (int k = threadIdx.x; k < NE; k += 1024) {
    float p = (float)counts[k] * (1.0f / (float)NTOK);
    s += p * logf(p + 1e-10f);
  }
#pragma unroll
  for (int m = 1; m < 64; m <<= 1) s += __shfl_xor(s, m);
  int lane = threadIdx.x & 63, wv = threadIdx.x >> 6;
  if (lane == 0) red[wv] = s;
  __syncthreads();
  if (threadIdx.x == 0) {
    float tot = 0.f;
    for (int i = 0; i < 16; ++i) tot += red[i];
    out[(size_t)NTOK * DIM] = expf(-tot);
  }
}

extern "C" void kernel_launch(void* const* d_in, const int* in_sizes, int n_in,
                              void* d_out, int out_size, void* d_ws, size_t ws_size,
                              hipStream_t stream) {
  const float* z = (const float*)d_in[0];
  const float* w = (const float*)d_in[1];
  float* out = (float*)d_out;
  char* ws = (char*)d_ws;

  unsigned char* zb     = (unsigned char*)(ws);
  float*        slot3   = (float*)(ws + 16777216);
  unsigned char* wb     = (unsigned char*)(ws + 33554432);
  float*        cnorm   = (float*)(ws + 41943040);
  float*        slot2   = (float*)(ws + 41975808);
  unsigned int* counts  = (unsigned int*)(ws + 75661312);

  k_prep_z<<<8192, 256, 0, stream>>>(z, (int2*)zb);
  k_prep_w<<<2048, 256, 0, stream>>>(w, (int2*)wb, cnorm);
  k_phase1<<<1024, 256, 0, stream>>>(zb, wb, cnorm, slot2, slot3);
  hipMemsetAsync(counts, 0, NE * sizeof(unsigned int), stream);
  k_select<<<8192, 256, 0, stream>>>(slot2, slot3, z, w, counts, out);
  k_perp<<<1, 1024, 0, stream>>>(counts, out);
}